// Round 2
// baseline (773.697 us; speedup 1.0000x reference)
//
#include <hip/hip_runtime.h>
#include <hip/hip_bf16.h>
#include <math.h>

#define Bdim 2
#define Cdim 256
#define Ndim 4096
#define HEADS 4
#define HDim 64
#define GROUPS 32

// ws layout in floats
static const size_t WS_STATS  = 0;          // 64*2, pad to 256
static const size_t WS_WTQKV  = 256;        // 256*768
static const size_t WS_WTPROJ = 196864;     // 256*256
static const size_t WS_HN     = 262400;     // 2*256*4096 (reused as attn_out)
static const size_t WS_QKV    = 2359552;    // 2*768*4096
// total = 8651008 floats = ~34.6 MB

// ---------------- weight transpose: W[O][C] -> WT[C][O] ----------------
__global__ __launch_bounds__(256) void tpose_k(const float* __restrict__ W,
                                               float* __restrict__ WT,
                                               int O, int Cc) {
    __shared__ float t[32][33];
    int c0 = blockIdx.x * 32, o0 = blockIdx.y * 32;
    int tx = threadIdx.x, ty = threadIdx.y;
#pragma unroll
    for (int k = 0; k < 4; k++) {
        int o = o0 + ty + k * 8;
        t[ty + k * 8][tx] = W[(size_t)o * Cc + c0 + tx];
    }
    __syncthreads();
#pragma unroll
    for (int k = 0; k < 4; k++) {
        int c = c0 + ty + k * 8;
        WT[(size_t)c * O + o0 + tx] = t[tx][ty + k * 8];
    }
}

// ---------------- group-norm stats: one block per (b,group) ----------------
__global__ __launch_bounds__(256) void gn_stats_k(const float* __restrict__ x,
                                                  float* __restrict__ stats) {
    int g = blockIdx.x;  // 0..63 ; group data is contiguous 32768 floats
    const float4* p4 = (const float4*)(x + (size_t)g * 32768);
    int tid = threadIdx.x;
    float s = 0.f, ss = 0.f;
#pragma unroll 8
    for (int w = 0; w < 32; w++) {
        float4 v = p4[tid + w * 256];
        s += v.x + v.y + v.z + v.w;
        ss += v.x * v.x + v.y * v.y + v.z * v.z + v.w * v.w;
    }
#pragma unroll
    for (int m = 1; m < 64; m <<= 1) {
        s += __shfl_xor(s, m);
        ss += __shfl_xor(ss, m);
    }
    __shared__ float ws_s[4], ws_ss[4];
    int wid = tid >> 6, lane = tid & 63;
    if (lane == 0) { ws_s[wid] = s; ws_ss[wid] = ss; }
    __syncthreads();
    if (tid == 0) {
        float ts = ws_s[0] + ws_s[1] + ws_s[2] + ws_s[3];
        float tss = ws_ss[0] + ws_ss[1] + ws_ss[2] + ws_ss[3];
        float mean = ts * (1.0f / 32768.0f);
        float var = tss * (1.0f / 32768.0f) - mean * mean;
        stats[2 * g] = mean;
        stats[2 * g + 1] = rsqrtf(var + 1e-5f);
    }
}

// ---------------- group-norm apply ----------------
__global__ __launch_bounds__(256) void gn_apply_k(const float* __restrict__ x,
                                                  const float* __restrict__ stats,
                                                  const float* __restrict__ scale,
                                                  const float* __restrict__ bias,
                                                  float* __restrict__ hn) {
    int i = blockIdx.x * 256 + threadIdx.x;  // one float4 per thread
    int f = i << 2;
    int c = (f >> 12) & 255;
    int b = f >> 20;
    int g = b * 32 + (c >> 3);
    float mean = stats[2 * g], rstd = stats[2 * g + 1];
    float sc = rstd * scale[c];
    float bi = bias[c] - mean * sc;
    float4 v = ((const float4*)x)[i];
    v.x = v.x * sc + bi; v.y = v.y * sc + bi; v.z = v.z * sc + bi; v.w = v.w * sc + bi;
    ((float4*)hn)[i] = v;
}

// ---------------- GEMM: out[b][o][n] = sum_c WT[c][o] * X[b][c][n] ----------------
// tiles 128(o) x 128(n), BK=32, 256 threads, 8x8 per thread (split 4+4 to kill
// the stride-8 4-way LDS bank conflict: each thread owns cols {t*4..t*4+3} and
// {64+t*4..64+t*4+3} -> ds_read_b128 at 16B stride = 2-way alias = free)
template <int O, bool EPI>
__global__ __launch_bounds__(256) void gemm_k(const float* __restrict__ WT,
                                              const float* __restrict__ X,
                                              float* __restrict__ out,
                                              const float* __restrict__ bias,
                                              const float* __restrict__ resid) {
    __shared__ __align__(16) float Ws[32][128];
    __shared__ __align__(16) float Xs[32][128];
    const int tid = threadIdx.x, tx = tid & 15, ty = tid >> 4;
    const int n0 = blockIdx.x << 7, o0 = blockIdx.y << 7;
    const size_t bX = (size_t)blockIdx.z * Cdim * Ndim;
    const size_t bO = (size_t)blockIdx.z * O * Ndim;
    float acc[8][8] = {};
    for (int k0 = 0; k0 < Cdim; k0 += 32) {
        __syncthreads();
#pragma unroll
        for (int kq = 0; kq < 4; kq++) {
            int f4 = tid + (kq << 8);
            int r = f4 >> 5, cc = (f4 & 31) << 2;
            *(float4*)&Ws[r][cc] = *(const float4*)(WT + (size_t)(k0 + r) * O + o0 + cc);
            *(float4*)&Xs[r][cc] = *(const float4*)(X + bX + (size_t)(k0 + r) * Ndim + n0 + cc);
        }
        __syncthreads();
#pragma unroll 4
        for (int kk = 0; kk < 32; kk++) {
            float4 wa = *(const float4*)&Ws[kk][ty << 2];
            float4 wb = *(const float4*)&Ws[kk][(ty << 2) + 64];
            float4 xa = *(const float4*)&Xs[kk][tx << 2];
            float4 xb = *(const float4*)&Xs[kk][(tx << 2) + 64];
            float w[8] = {wa.x, wa.y, wa.z, wa.w, wb.x, wb.y, wb.z, wb.w};
            float xv[8] = {xa.x, xa.y, xa.z, xa.w, xb.x, xb.y, xb.z, xb.w};
#pragma unroll
            for (int i = 0; i < 8; i++)
#pragma unroll
                for (int j = 0; j < 8; j++)
                    acc[i][j] = fmaf(w[i], xv[j], acc[i][j]);
        }
    }
    // epilogue: thread covers o in {o0+ty*4+i, o0+64+ty*4+i}, n in {n0+tx*4+j, n0+64+tx*4+j}
#pragma unroll
    for (int i = 0; i < 8; i++) {
        int o = o0 + (ty << 2) + ((i < 4) ? i : (64 + i - 4));
        size_t rowoff = bO + (size_t)o * Ndim + n0 + (tx << 2);
        float bv = EPI ? bias[o] : 0.0f;
        float4 r0, r1;
        r0.x = acc[i][0] + bv; r0.y = acc[i][1] + bv; r0.z = acc[i][2] + bv; r0.w = acc[i][3] + bv;
        r1.x = acc[i][4] + bv; r1.y = acc[i][5] + bv; r1.z = acc[i][6] + bv; r1.w = acc[i][7] + bv;
        if (EPI) {
            size_t xoff = bX + (size_t)o * Ndim + n0 + (tx << 2);
            float4 x0 = *(const float4*)(resid + xoff);
            float4 x1 = *(const float4*)(resid + xoff + 64);
            r0.x += x0.x; r0.y += x0.y; r0.z += x0.z; r0.w += x0.w;
            r1.x += x1.x; r1.y += x1.y; r1.z += x1.z; r1.w += x1.w;
        }
        *(float4*)(out + rowoff) = r0;
        *(float4*)(out + rowoff + 64) = r1;
    }
}

// ---------------- flash attention, fp32 ----------------
// grid (64 qtiles, 4 heads, 2 batch), 256 threads
// Q,K,V layouts: [d][n] per (b,h). QB=KB=64, 4x4 per thread.
__global__ __launch_bounds__(256) void attn_k(const float* __restrict__ qkv,
                                              float* __restrict__ outp) {
    __shared__ __align__(16) float Qs[64][64];
    __shared__ __align__(16) float Ks[64][64];
    __shared__ __align__(16) float Vs[64][68];  // [m][d] (transposed), padded
    __shared__ __align__(16) float Ps[64][68];  // [m][q] P^T, padded; reused for out staging [d][q]
    const int tid = threadIdx.x, tx = tid & 15, ty = tid >> 4;
    const int qt = blockIdx.x, h = blockIdx.y, b = blockIdx.z;
    const size_t hb = (size_t)b * 3 * Cdim * Ndim + (size_t)h * HDim * Ndim;
    const float* Qg = qkv + hb;
    const float* Kg = qkv + hb + (size_t)Cdim * Ndim;
    const float* Vg = qkv + hb + (size_t)2 * Cdim * Ndim;

    // load Q tile, fold in softmax scale 1/sqrt(64)
#pragma unroll
    for (int kq = 0; kq < 4; kq++) {
        int f = tid + (kq << 8);
        int r = f >> 4, cc = (f & 15) << 2;
        float4 v = *(const float4*)(Qg + (size_t)r * Ndim + qt * 64 + cc);
        v.x *= 0.125f; v.y *= 0.125f; v.z *= 0.125f; v.w *= 0.125f;
        *(float4*)&Qs[r][cc] = v;
    }

    float acc[4][4] = {};
    float mrun[4] = {-1e30f, -1e30f, -1e30f, -1e30f};
    float lrun[4] = {0.f, 0.f, 0.f, 0.f};

    for (int m0 = 0; m0 < Ndim; m0 += 64) {
        __syncthreads();  // prev PV done with Vs/Ps (also covers Q load on iter 0)
#pragma unroll
        for (int kq = 0; kq < 4; kq++) {
            int f = tid + (kq << 8);
            int r = f >> 4, cc = (f & 15) << 2;
            *(float4*)&Ks[r][cc] = *(const float4*)(Kg + (size_t)r * Ndim + m0 + cc);
            float4 v = *(const float4*)(Vg + (size_t)r * Ndim + m0 + cc);
            Vs[cc + 0][r] = v.x; Vs[cc + 1][r] = v.y; Vs[cc + 2][r] = v.z; Vs[cc + 3][r] = v.w;
        }
        __syncthreads();

        // S = (Q^T K) tile : thread -> q = 4*ty+i, m = 4*tx+j
        float s[4][4] = {};
#pragma unroll 8
        for (int kk = 0; kk < 64; kk++) {
            float4 qv = *(const float4*)&Qs[kk][ty << 2];
            float4 kv = *(const float4*)&Ks[kk][tx << 2];
            float qa[4] = {qv.x, qv.y, qv.z, qv.w};
            float ka[4] = {kv.x, kv.y, kv.z, kv.w};
#pragma unroll
            for (int i = 0; i < 4; i++)
#pragma unroll
                for (int j = 0; j < 4; j++)
                    s[i][j] = fmaf(qa[i], ka[j], s[i][j]);
        }

        // online softmax per query row (row spread across 16 tx lanes)
#pragma unroll
        for (int i = 0; i < 4; i++) {
            float mx = fmaxf(fmaxf(s[i][0], s[i][1]), fmaxf(s[i][2], s[i][3]));
            mx = fmaxf(mx, __shfl_xor(mx, 1));
            mx = fmaxf(mx, __shfl_xor(mx, 2));
            mx = fmaxf(mx, __shfl_xor(mx, 4));
            mx = fmaxf(mx, __shfl_xor(mx, 8));
            float mn = fmaxf(mrun[i], mx);
            float al = __expf(mrun[i] - mn);
            float rs = 0.f;
#pragma unroll
            for (int j = 0; j < 4; j++) {
                s[i][j] = __expf(s[i][j] - mn);
                rs += s[i][j];
            }
            rs += __shfl_xor(rs, 1);
            rs += __shfl_xor(rs, 2);
            rs += __shfl_xor(rs, 4);
            rs += __shfl_xor(rs, 8);
            lrun[i] = lrun[i] * al + rs;
            mrun[i] = mn;
#pragma unroll
            for (int j = 0; j < 4; j++) acc[i][j] *= al;
        }

        // write P^T to LDS (tx-rotated store order to spread banks)
#pragma unroll
        for (int jj = 0; jj < 4; jj++) {
            int j = (jj + tx) & 3;
#pragma unroll
            for (int i = 0; i < 4; i++)
                Ps[(tx << 2) + j][(ty << 2) + i] = s[i][j];
        }
        __syncthreads();

        // acc[q][d] += sum_m P^T[m][q] * V^T[m][d]
#pragma unroll 8
        for (int mm = 0; mm < 64; mm++) {
            float4 pv = *(const float4*)&Ps[mm][ty << 2];
            float4 vv = *(const float4*)&Vs[mm][tx << 2];
            float pa[4] = {pv.x, pv.y, pv.z, pv.w};
            float va[4] = {vv.x, vv.y, vv.z, vv.w};
#pragma unroll
            for (int i = 0; i < 4; i++)
#pragma unroll
                for (int j = 0; j < 4; j++)
                    acc[i][j] = fmaf(pa[i], va[j], acc[i][j]);
        }
    }

    __syncthreads();  // all PV reads of Ps done
    // stage normalized output as [d][q] in Ps
#pragma unroll
    for (int i = 0; i < 4; i++) {
        float inv = 1.0f / lrun[i];
#pragma unroll
        for (int jj = 0; jj < 4; jj++) {
            int j = (jj + tx) & 3;
            Ps[(tx << 2) + j][(ty << 2) + i] = acc[i][j] * inv;
        }
    }
    __syncthreads();
    float* Og = outp + (size_t)b * Cdim * Ndim + (size_t)h * HDim * Ndim + (size_t)qt * 64;
#pragma unroll
    for (int kq = 0; kq < 4; kq++) {
        int f = tid + (kq << 8);
        int r = f >> 4, cc = (f & 15) << 2;
        *(float4*)(Og + (size_t)r * Ndim + cc) = *(const float4*)&Ps[r][cc];
    }
}

extern "C" void kernel_launch(void* const* d_in, const int* in_sizes, int n_in,
                              void* d_out, int out_size, void* d_ws, size_t ws_size,
                              hipStream_t stream) {
    (void)in_sizes; (void)n_in; (void)out_size; (void)ws_size;
    const float* x        = (const float*)d_in[0];
    const float* gn_scale = (const float*)d_in[1];
    const float* gn_bias  = (const float*)d_in[2];
    const float* w_qkv    = (const float*)d_in[3];
    const float* w_proj   = (const float*)d_in[4];
    const float* b_proj   = (const float*)d_in[5];
    float* ws    = (float*)d_ws;
    float* stats = ws + WS_STATS;
    float* wtq   = ws + WS_WTQKV;
    float* wtp   = ws + WS_WTPROJ;
    float* hn    = ws + WS_HN;    // reused as attention output
    float* qkvb  = ws + WS_QKV;
    float* outp  = (float*)d_out;

    tpose_k<<<dim3(8, 24), dim3(32, 8), 0, stream>>>(w_qkv, wtq, 768, 256);
    tpose_k<<<dim3(8, 8), dim3(32, 8), 0, stream>>>(w_proj, wtp, 256, 256);
    gn_stats_k<<<64, 256, 0, stream>>>(x, stats);
    gn_apply_k<<<2048, 256, 0, stream>>>(x, stats, gn_scale, gn_bias, hn);
    gemm_k<768, false><<<dim3(32, 6, 2), 256, 0, stream>>>(wtq, hn, qkvb, nullptr, nullptr);
    attn_k<<<dim3(64, 4, 2), 256, 0, stream>>>(qkvb, hn);
    gemm_k<256, true><<<dim3(32, 2, 2), 256, 0, stream>>>(wtp, hn, outp, b_proj, x);
}

// Round 3
// 400.726 us; speedup vs baseline: 1.9307x; 1.9307x over previous
//
#include <hip/hip_runtime.h>
#include <hip/hip_bf16.h>
#include <math.h>

#define Bdim 2
#define Cdim 256
#define Ndim 4096
#define HEADS 4
#define HDim 64

typedef _Float16 half8 __attribute__((ext_vector_type(8)));
typedef _Float16 half4 __attribute__((ext_vector_type(4)));
typedef float f32x4 __attribute__((ext_vector_type(4)));

// ws layout in floats
static const size_t WS_STATS  = 0;        // 64*2 -> pad 256
static const size_t WS_WTQKV  = 256;      // 256*768 fp32
static const size_t WS_WTPROJ = 196864;   // 256*256 fp32
static const size_t WS_HN     = 262400;   // 2*256*4096 fp32 (GN out, reused as attn out)
static const size_t WS_QT     = 2359552;  // 2*4*4096*64 f16 = 1048576 floats
static const size_t WS_KT     = 3408128;  // same
static const size_t WS_VF     = 4456704;  // 2*256*4096 f16 = 1048576 floats
// end 5505280 floats = 22 MB (< previously-validated 34.6 MB ws)

// ---------------- weight transpose: W[O][C] -> WT[C][O] ----------------
__global__ __launch_bounds__(256) void tpose_k(const float* __restrict__ W,
                                               float* __restrict__ WT,
                                               int O, int Cc) {
    __shared__ float t[32][33];
    int c0 = blockIdx.x * 32, o0 = blockIdx.y * 32;
    int tx = threadIdx.x, ty = threadIdx.y;
#pragma unroll
    for (int k = 0; k < 4; k++) {
        int o = o0 + ty + k * 8;
        t[ty + k * 8][tx] = W[(size_t)o * Cc + c0 + tx];
    }
    __syncthreads();
#pragma unroll
    for (int k = 0; k < 4; k++) {
        int c = c0 + ty + k * 8;
        WT[(size_t)c * O + o0 + tx] = t[tx][ty + k * 8];
    }
}

// ---------------- group-norm stats ----------------
__global__ __launch_bounds__(256) void gn_stats_k(const float* __restrict__ x,
                                                  float* __restrict__ stats) {
    int g = blockIdx.x;
    const float4* p4 = (const float4*)(x + (size_t)g * 32768);
    int tid = threadIdx.x;
    float s = 0.f, ss = 0.f;
#pragma unroll 8
    for (int w = 0; w < 32; w++) {
        float4 v = p4[tid + w * 256];
        s += v.x + v.y + v.z + v.w;
        ss += v.x * v.x + v.y * v.y + v.z * v.z + v.w * v.w;
    }
#pragma unroll
    for (int m = 1; m < 64; m <<= 1) {
        s += __shfl_xor(s, m);
        ss += __shfl_xor(ss, m);
    }
    __shared__ float ws_s[4], ws_ss[4];
    int wid = tid >> 6, lane = tid & 63;
    if (lane == 0) { ws_s[wid] = s; ws_ss[wid] = ss; }
    __syncthreads();
    if (tid == 0) {
        float ts = ws_s[0] + ws_s[1] + ws_s[2] + ws_s[3];
        float tss = ws_ss[0] + ws_ss[1] + ws_ss[2] + ws_ss[3];
        float mean = ts * (1.0f / 32768.0f);
        float var = tss * (1.0f / 32768.0f) - mean * mean;
        stats[2 * g] = mean;
        stats[2 * g + 1] = rsqrtf(var + 1e-5f);
    }
}

// ---------------- group-norm apply ----------------
__global__ __launch_bounds__(256) void gn_apply_k(const float* __restrict__ x,
                                                  const float* __restrict__ stats,
                                                  const float* __restrict__ scale,
                                                  const float* __restrict__ bias,
                                                  float* __restrict__ hn) {
    int i = blockIdx.x * 256 + threadIdx.x;
    int f = i << 2;
    int c = (f >> 12) & 255;
    int b = f >> 20;
    int g = b * 32 + (c >> 3);
    float mean = stats[2 * g], rstd = stats[2 * g + 1];
    float sc = rstd * scale[c];
    float bi = bias[c] - mean * sc;
    float4 v = ((const float4*)x)[i];
    v.x = v.x * sc + bi; v.y = v.y * sc + bi; v.z = v.z * sc + bi; v.w = v.w * sc + bi;
    ((float4*)hn)[i] = v;
}

// ---------------- QKV GEMM (fp32 core) with f16 attention-layout epilogue ----
// out o-sections: [0,256)=q -> qT[b][h][n][d]*0.125 ; [256,512)=k -> kT[b][h][n][d];
// [512,768)=v -> vF[b][h*64+d][n]
__global__ __launch_bounds__(256) void gemm_qkv_k(const float* __restrict__ WT,
                                                  const float* __restrict__ X,
                                                  _Float16* __restrict__ qT,
                                                  _Float16* __restrict__ kT,
                                                  _Float16* __restrict__ vF) {
    __shared__ __align__(16) float Ws[32][128];
    __shared__ __align__(16) float Xs[32][128];
    const int tid = threadIdx.x, tx = tid & 15, ty = tid >> 4;
    const int n0 = blockIdx.x << 7, o0 = blockIdx.y << 7;
    const int bz = blockIdx.z;
    const size_t bX = (size_t)bz * Cdim * Ndim;
    float acc[8][8] = {};
    for (int k0 = 0; k0 < Cdim; k0 += 32) {
        __syncthreads();
#pragma unroll
        for (int kq = 0; kq < 4; kq++) {
            int f4 = tid + (kq << 8);
            int r = f4 >> 5, cc = (f4 & 31) << 2;
            *(float4*)&Ws[r][cc] = *(const float4*)(WT + (size_t)(k0 + r) * 768 + o0 + cc);
            *(float4*)&Xs[r][cc] = *(const float4*)(X + bX + (size_t)(k0 + r) * Ndim + n0 + cc);
        }
        __syncthreads();
#pragma unroll 4
        for (int kk = 0; kk < 32; kk++) {
            float4 wa = *(const float4*)&Ws[kk][ty << 2];
            float4 wb = *(const float4*)&Ws[kk][(ty << 2) + 64];
            float4 xa = *(const float4*)&Xs[kk][tx << 2];
            float4 xb = *(const float4*)&Xs[kk][(tx << 2) + 64];
            float w[8] = {wa.x, wa.y, wa.z, wa.w, wb.x, wb.y, wb.z, wb.w};
            float xv[8] = {xa.x, xa.y, xa.z, xa.w, xb.x, xb.y, xb.z, xb.w};
#pragma unroll
            for (int i = 0; i < 8; i++)
#pragma unroll
                for (int j = 0; j < 8; j++)
                    acc[i][j] = fmaf(w[i], xv[j], acc[i][j]);
        }
    }
    if (o0 < 512) {
        // q or k: transposed f16 store [b][h][n][d], 4 consecutive d per half4
        const int sec = o0 >> 8;  // 0=q, 1=k
        _Float16* dst = sec ? kT : qT;
        const float qs = sec ? 1.0f : 0.125f;
        const int oss = o0 & 255;  // 0 or 128
#pragma unroll
        for (int g = 0; g < 2; g++) {
            int hh = (oss >> 6) + g;
            _Float16* hb = dst + ((size_t)(bz * 4 + hh) * Ndim) * 64 + (ty << 2);
#pragma unroll
            for (int j = 0; j < 8; j++) {
                int n = n0 + (tx << 2) + (j & 3) + ((j >> 2) << 6);
                half4 hv;
                hv[0] = (_Float16)(acc[g * 4 + 0][j] * qs);
                hv[1] = (_Float16)(acc[g * 4 + 1][j] * qs);
                hv[2] = (_Float16)(acc[g * 4 + 2][j] * qs);
                hv[3] = (_Float16)(acc[g * 4 + 3][j] * qs);
                *(half4*)(hb + (size_t)n * 64) = hv;
            }
        }
    } else {
        // v: natural f16 store [b][256 rows][n]
#pragma unroll
        for (int i = 0; i < 8; i++) {
            int row = (o0 - 512) + (ty << 2) + (i & 3) + ((i >> 2) << 6);
            _Float16* rb = vF + ((size_t)bz * 256 + row) * Ndim + n0 + (tx << 2);
#pragma unroll
            for (int jg = 0; jg < 2; jg++) {
                half4 hv;
                hv[0] = (_Float16)acc[i][jg * 4 + 0];
                hv[1] = (_Float16)acc[i][jg * 4 + 1];
                hv[2] = (_Float16)acc[i][jg * 4 + 2];
                hv[3] = (_Float16)acc[i][jg * 4 + 3];
                *(half4*)(rb + (jg << 6)) = hv;
            }
        }
    }
}

// ---------------- flash attention, f16 MFMA ----------------
// grid (64,4,2), 256 thr = 4 waves; wave w owns q rows [qt*64+16w, +16), KB=32.
// A-frag(16x16x32): row=lane&15, k=(lane>>4)*8+i ; B-frag: col=lane&15, same k.
// C/D: col=lane&15, row=(lane>>4)*4+reg.
__global__ __launch_bounds__(256) void attn_k(const _Float16* __restrict__ qT,
                                              const _Float16* __restrict__ kT,
                                              const _Float16* __restrict__ vF,
                                              float* __restrict__ outp) {
    __shared__ __align__(16) char smem[4096 + 16384];  // Ps (f16 64x32) + LdsO (f32 64x64)
    char* PsB = smem;
    char* LoB = smem + 4096;
    const int tid = threadIdx.x;
    const int w = tid >> 6, lane = tid & 63;
    const int a = lane >> 4, b_ = lane & 15;
    const int qt = blockIdx.x, h = blockIdx.y, bz = blockIdx.z;
    const int q0 = qt * 64;
    const size_t bh = (size_t)(bz * 4 + h);
    const _Float16* Qb = qT + bh * (size_t)(Ndim * 64);
    const _Float16* Kb = kT + bh * (size_t)(Ndim * 64);
    const _Float16* Vb = vF + bh * (size_t)(64 * Ndim);

    // Q fragments (scale already folded in qT)
    const _Float16* qp = Qb + (size_t)(q0 + w * 16 + b_) * 64 + a * 8;
    half8 qf0 = *(const half8*)(qp);
    half8 qf1 = *(const half8*)(qp + 32);

    f32x4 o0 = {0.f, 0.f, 0.f, 0.f}, o1 = o0, o2 = o0, o3 = o0;
    float mr[4] = {-1e30f, -1e30f, -1e30f, -1e30f};
    float lr[4] = {0.f, 0.f, 0.f, 0.f};

    const int prd = (((w * 16 + b_) * 64 + a * 16) ^ ((b_ & 12) << 2));

    for (int m0 = 0; m0 < Ndim; m0 += 32) {
        const _Float16* Kt = Kb + (size_t)(m0 + b_) * 64 + a * 8;
        half8 k00 = *(const half8*)(Kt);
        half8 k01 = *(const half8*)(Kt + 32);
        half8 k10 = *(const half8*)(Kt + 16 * 64);
        half8 k11 = *(const half8*)(Kt + 16 * 64 + 32);
        const _Float16* Vt = Vb + (size_t)b_ * Ndim + m0 + a * 8;
        half8 v0 = *(const half8*)(Vt);
        half8 v1 = *(const half8*)(Vt + 16 * Ndim);
        half8 v2 = *(const half8*)(Vt + 32 * Ndim);
        half8 v3 = *(const half8*)(Vt + 48 * Ndim);

        f32x4 s0 = {0.f, 0.f, 0.f, 0.f}, s1 = s0;
        s0 = __builtin_amdgcn_mfma_f32_16x16x32_f16(qf0, k00, s0, 0, 0, 0);
        s0 = __builtin_amdgcn_mfma_f32_16x16x32_f16(qf1, k01, s0, 0, 0, 0);
        s1 = __builtin_amdgcn_mfma_f32_16x16x32_f16(qf0, k10, s1, 0, 0, 0);
        s1 = __builtin_amdgcn_mfma_f32_16x16x32_f16(qf1, k11, s1, 0, 0, 0);

        float al[4], e0[4], e1[4];
#pragma unroll
        for (int r = 0; r < 4; r++) {
            float mx = fmaxf(s0[r], s1[r]);
            mx = fmaxf(mx, __shfl_xor(mx, 1));
            mx = fmaxf(mx, __shfl_xor(mx, 2));
            mx = fmaxf(mx, __shfl_xor(mx, 4));
            mx = fmaxf(mx, __shfl_xor(mx, 8));
            float mn = fmaxf(mr[r], mx);
            al[r] = __expf(mr[r] - mn);
            e0[r] = __expf(s0[r] - mn);
            e1[r] = __expf(s1[r] - mn);
            float rs = e0[r] + e1[r];
            rs += __shfl_xor(rs, 1);
            rs += __shfl_xor(rs, 2);
            rs += __shfl_xor(rs, 4);
            rs += __shfl_xor(rs, 8);
            lr[r] = lr[r] * al[r] + rs;
            mr[r] = mn;
        }
#pragma unroll
        for (int r = 0; r < 4; r++) {
            o0[r] *= al[r]; o1[r] *= al[r]; o2[r] *= al[r]; o3[r] *= al[r];
        }
        // P -> LDS f16 (swizzled, wave-local rows; no barrier needed)
#pragma unroll
        for (int r = 0; r < 4; r++) {
            int ql = w * 16 + a * 4 + r;
            int base = ql * 64 + b_ * 2;
            int sw = (ql & 12) << 2;
            *(_Float16*)(PsB + ((base) ^ sw)) = (_Float16)e0[r];
            *(_Float16*)(PsB + ((base + 32) ^ sw)) = (_Float16)e1[r];
        }
        half8 pa = *(half8*)(PsB + prd);
        o0 = __builtin_amdgcn_mfma_f32_16x16x32_f16(pa, v0, o0, 0, 0, 0);
        o1 = __builtin_amdgcn_mfma_f32_16x16x32_f16(pa, v1, o1, 0, 0, 0);
        o2 = __builtin_amdgcn_mfma_f32_16x16x32_f16(pa, v2, o2, 0, 0, 0);
        o3 = __builtin_amdgcn_mfma_f32_16x16x32_f16(pa, v3, o3, 0, 0, 0);
    }

    float inv[4];
#pragma unroll
    for (int r = 0; r < 4; r++) inv[r] = 1.0f / lr[r];
    // stage O^T[d][q] in LDS (swizzled), then coalesced global store
#pragma unroll
    for (int dt = 0; dt < 4; dt++) {
        f32x4 val = (dt == 0) ? o0 : (dt == 1) ? o1 : (dt == 2) ? o2 : o3;
#pragma unroll
        for (int r = 0; r < 4; r++) val[r] *= inv[r];
        int d = 16 * dt + b_;
        int off = (d * 256 + w * 64 + a * 16) ^ ((d & 7) << 4);
        *(f32x4*)(LoB + off) = val;
    }
    __syncthreads();
#pragma unroll
    for (int p = 0; p < 4; p++) {
        int d = p * 16 + (tid >> 4), qc = tid & 15;
        int off = (d * 256 + qc * 16) ^ ((d & 7) << 4);
        f32x4 v = *(f32x4*)(LoB + off);
        *(f32x4*)(outp + ((size_t)bz * 256 + h * 64 + d) * Ndim + q0 + (qc << 2)) = v;
    }
}

// ---------------- proj GEMM (fp32) with bias+residual epilogue ----------------
__global__ __launch_bounds__(256) void gemm_proj_k(const float* __restrict__ WT,
                                                   const float* __restrict__ X,
                                                   float* __restrict__ out,
                                                   const float* __restrict__ bias,
                                                   const float* __restrict__ resid) {
    __shared__ __align__(16) float Ws[32][128];
    __shared__ __align__(16) float Xs[32][128];
    const int tid = threadIdx.x, tx = tid & 15, ty = tid >> 4;
    const int n0 = blockIdx.x << 7, o0 = blockIdx.y << 7;
    const size_t bX = (size_t)blockIdx.z * Cdim * Ndim;
    float acc[8][8] = {};
    for (int k0 = 0; k0 < Cdim; k0 += 32) {
        __syncthreads();
#pragma unroll
        for (int kq = 0; kq < 4; kq++) {
            int f4 = tid + (kq << 8);
            int r = f4 >> 5, cc = (f4 & 31) << 2;
            *(float4*)&Ws[r][cc] = *(const float4*)(WT + (size_t)(k0 + r) * 256 + o0 + cc);
            *(float4*)&Xs[r][cc] = *(const float4*)(X + bX + (size_t)(k0 + r) * Ndim + n0 + cc);
        }
        __syncthreads();
#pragma unroll 4
        for (int kk = 0; kk < 32; kk++) {
            float4 wa = *(const float4*)&Ws[kk][ty << 2];
            float4 wb = *(const float4*)&Ws[kk][(ty << 2) + 64];
            float4 xa = *(const float4*)&Xs[kk][tx << 2];
            float4 xb = *(const float4*)&Xs[kk][(tx << 2) + 64];
            float w[8] = {wa.x, wa.y, wa.z, wa.w, wb.x, wb.y, wb.z, wb.w};
            float xv[8] = {xa.x, xa.y, xa.z, xa.w, xb.x, xb.y, xb.z, xb.w};
#pragma unroll
            for (int i = 0; i < 8; i++)
#pragma unroll
                for (int j = 0; j < 8; j++)
                    acc[i][j] = fmaf(w[i], xv[j], acc[i][j]);
        }
    }
#pragma unroll
    for (int i = 0; i < 8; i++) {
        int o = o0 + (ty << 2) + ((i < 4) ? i : (64 + i - 4));
        size_t rowoff = bX + (size_t)o * Ndim + n0 + (tx << 2);
        float bv = bias[o];
        float4 r0, r1;
        r0.x = acc[i][0] + bv; r0.y = acc[i][1] + bv; r0.z = acc[i][2] + bv; r0.w = acc[i][3] + bv;
        r1.x = acc[i][4] + bv; r1.y = acc[i][5] + bv; r1.z = acc[i][6] + bv; r1.w = acc[i][7] + bv;
        float4 x0 = *(const float4*)(resid + rowoff);
        float4 x1 = *(const float4*)(resid + rowoff + 64);
        r0.x += x0.x; r0.y += x0.y; r0.z += x0.z; r0.w += x0.w;
        r1.x += x1.x; r1.y += x1.y; r1.z += x1.z; r1.w += x1.w;
        *(float4*)(out + rowoff) = r0;
        *(float4*)(out + rowoff + 64) = r1;
    }
}

extern "C" void kernel_launch(void* const* d_in, const int* in_sizes, int n_in,
                              void* d_out, int out_size, void* d_ws, size_t ws_size,
                              hipStream_t stream) {
    (void)in_sizes; (void)n_in; (void)out_size; (void)ws_size;
    const float* x        = (const float*)d_in[0];
    const float* gn_scale = (const float*)d_in[1];
    const float* gn_bias  = (const float*)d_in[2];
    const float* w_qkv    = (const float*)d_in[3];
    const float* w_proj   = (const float*)d_in[4];
    const float* b_proj   = (const float*)d_in[5];
    float* ws    = (float*)d_ws;
    float* stats = ws + WS_STATS;
    float* wtq   = ws + WS_WTQKV;
    float* wtp   = ws + WS_WTPROJ;
    float* hn    = ws + WS_HN;   // GN out; later attn out
    _Float16* qT = (_Float16*)(ws + WS_QT);
    _Float16* kT = (_Float16*)(ws + WS_KT);
    _Float16* vF = (_Float16*)(ws + WS_VF);
    float* outp  = (float*)d_out;

    tpose_k<<<dim3(8, 24), dim3(32, 8), 0, stream>>>(w_qkv, wtq, 768, 256);
    tpose_k<<<dim3(8, 8), dim3(32, 8), 0, stream>>>(w_proj, wtp, 256, 256);
    gn_stats_k<<<64, 256, 0, stream>>>(x, stats);
    gn_apply_k<<<2048, 256, 0, stream>>>(x, stats, gn_scale, gn_bias, hn);
    gemm_qkv_k<<<dim3(32, 6, 2), 256, 0, stream>>>(wtq, hn, qT, kT, vF);
    attn_k<<<dim3(64, 4, 2), 256, 0, stream>>>(qT, kT, vF, hn);
    gemm_proj_k<<<dim3(32, 2, 2), 256, 0, stream>>>(wtp, hn, outp, b_proj, x);
}

// Round 5
// 271.649 us; speedup vs baseline: 2.8481x; 1.4752x over previous
//
#include <hip/hip_runtime.h>
#include <hip/hip_bf16.h>
#include <math.h>

#define Bdim 2
#define Cdim 256
#define Ndim 4096
#define HEADS 4
#define HDim 64

typedef _Float16 half8 __attribute__((ext_vector_type(8)));
typedef _Float16 half4 __attribute__((ext_vector_type(4)));
typedef float f32x4 __attribute__((ext_vector_type(4)));

// ws layout in floats
static const size_t WS_STATS  = 0;        // 64*2 -> pad 256
static const size_t WS_WTQKV  = 256;      // 256*768 fp32
static const size_t WS_WTPROJ = 196864;   // 256*256 fp32
static const size_t WS_HN     = 262400;   // 2*256*4096 fp32 (GN out, reused as attn out)
static const size_t WS_QT     = 2359552;  // 2*4*4096*64 f16
static const size_t WS_KT     = 3408128;
static const size_t WS_VF     = 4456704;  // 2*256*4096 f16
// end 5505280 floats = 22 MB

// q scale: 1/sqrt(64) * log2(e), so MFMA S' = log2(e)*S_true; acc init -8.65617
// gives P = 2^(S'-8.656) = e^(S_true-6); the e^-6 cancels in the normalize.
#define QSCALE 0.18033688f
#define SINIT  -8.65617025f

// DPP helpers: reduce over 16-lane rows on the VALU pipe (no LDS traffic)
#define DPP_ADD(x, ctrl)                                                          \
    {                                                                             \
        int _y = __builtin_amdgcn_update_dpp(0, __float_as_int(x), ctrl, 0xf, 0xf, false); \
        x += __int_as_float(_y);                                                  \
    }

// ---------------- weight transpose: W[O][C] -> WT[C][O] ----------------
__global__ __launch_bounds__(256) void tpose_k(const float* __restrict__ W,
                                               float* __restrict__ WT,
                                               int O, int Cc) {
    __shared__ float t[32][33];
    int c0 = blockIdx.x * 32, o0 = blockIdx.y * 32;
    int tx = threadIdx.x, ty = threadIdx.y;
#pragma unroll
    for (int k = 0; k < 4; k++) {
        int o = o0 + ty + k * 8;
        t[ty + k * 8][tx] = W[(size_t)o * Cc + c0 + tx];
    }
    __syncthreads();
#pragma unroll
    for (int k = 0; k < 4; k++) {
        int c = c0 + ty + k * 8;
        WT[(size_t)c * O + o0 + tx] = t[tx][ty + k * 8];
    }
}

// ---------------- group-norm stats ----------------
__global__ __launch_bounds__(256) void gn_stats_k(const float* __restrict__ x,
                                                  float* __restrict__ stats) {
    int g = blockIdx.x;
    const float4* p4 = (const float4*)(x + (size_t)g * 32768);
    int tid = threadIdx.x;
    float s = 0.f, ss = 0.f;
#pragma unroll 8
    for (int w = 0; w < 32; w++) {
        float4 v = p4[tid + w * 256];
        s += v.x + v.y + v.z + v.w;
        ss += v.x * v.x + v.y * v.y + v.z * v.z + v.w * v.w;
    }
#pragma unroll
    for (int m = 1; m < 64; m <<= 1) {
        s += __shfl_xor(s, m);
        ss += __shfl_xor(ss, m);
    }
    __shared__ float ws_s[4], ws_ss[4];
    int wid = tid >> 6, lane = tid & 63;
    if (lane == 0) { ws_s[wid] = s; ws_ss[wid] = ss; }
    __syncthreads();
    if (tid == 0) {
        float ts = ws_s[0] + ws_s[1] + ws_s[2] + ws_s[3];
        float tss = ws_ss[0] + ws_ss[1] + ws_ss[2] + ws_ss[3];
        float mean = ts * (1.0f / 32768.0f);
        float var = tss * (1.0f / 32768.0f) - mean * mean;
        stats[2 * g] = mean;
        stats[2 * g + 1] = rsqrtf(var + 1e-5f);
    }
}

// ---------------- group-norm apply ----------------
__global__ __launch_bounds__(256) void gn_apply_k(const float* __restrict__ x,
                                                  const float* __restrict__ stats,
                                                  const float* __restrict__ scale,
                                                  const float* __restrict__ bias,
                                                  float* __restrict__ hn) {
    int i = blockIdx.x * 256 + threadIdx.x;
    int f = i << 2;
    int c = (f >> 12) & 255;
    int b = f >> 20;
    int g = b * 32 + (c >> 3);
    float mean = stats[2 * g], rstd = stats[2 * g + 1];
    float sc = rstd * scale[c];
    float bi = bias[c] - mean * sc;
    float4 v = ((const float4*)x)[i];
    v.x = v.x * sc + bi; v.y = v.y * sc + bi; v.z = v.z * sc + bi; v.w = v.w * sc + bi;
    ((float4*)hn)[i] = v;
}

// ---------------- QKV GEMM (fp32 core) with f16 attention-layout epilogue ----
__global__ __launch_bounds__(256) void gemm_qkv_k(const float* __restrict__ WT,
                                                  const float* __restrict__ X,
                                                  _Float16* __restrict__ qT,
                                                  _Float16* __restrict__ kT,
                                                  _Float16* __restrict__ vF) {
    __shared__ __align__(16) float Ws[32][128];
    __shared__ __align__(16) float Xs[32][128];
    const int tid = threadIdx.x, tx = tid & 15, ty = tid >> 4;
    const int n0 = blockIdx.x << 7, o0 = blockIdx.y << 7;
    const int bz = blockIdx.z;
    const size_t bX = (size_t)bz * Cdim * Ndim;
    float acc[8][8] = {};
    for (int k0 = 0; k0 < Cdim; k0 += 32) {
        __syncthreads();
#pragma unroll
        for (int kq = 0; kq < 4; kq++) {
            int f4 = tid + (kq << 8);
            int r = f4 >> 5, cc = (f4 & 31) << 2;
            *(float4*)&Ws[r][cc] = *(const float4*)(WT + (size_t)(k0 + r) * 768 + o0 + cc);
            *(float4*)&Xs[r][cc] = *(const float4*)(X + bX + (size_t)(k0 + r) * Ndim + n0 + cc);
        }
        __syncthreads();
#pragma unroll 4
        for (int kk = 0; kk < 32; kk++) {
            float4 wa = *(const float4*)&Ws[kk][ty << 2];
            float4 wb = *(const float4*)&Ws[kk][(ty << 2) + 64];
            float4 xa = *(const float4*)&Xs[kk][tx << 2];
            float4 xb = *(const float4*)&Xs[kk][(tx << 2) + 64];
            float w[8] = {wa.x, wa.y, wa.z, wa.w, wb.x, wb.y, wb.z, wb.w};
            float xv[8] = {xa.x, xa.y, xa.z, xa.w, xb.x, xb.y, xb.z, xb.w};
#pragma unroll
            for (int i = 0; i < 8; i++)
#pragma unroll
                for (int j = 0; j < 8; j++)
                    acc[i][j] = fmaf(w[i], xv[j], acc[i][j]);
        }
    }
    if (o0 < 512) {
        const int sec = o0 >> 8;  // 0=q, 1=k
        _Float16* dst = sec ? kT : qT;
        const float qs = sec ? 1.0f : QSCALE;
        const int oss = o0 & 255;
#pragma unroll
        for (int g = 0; g < 2; g++) {
            int hh = (oss >> 6) + g;
            _Float16* hb = dst + ((size_t)(bz * 4 + hh) * Ndim) * 64 + (ty << 2);
#pragma unroll
            for (int j = 0; j < 8; j++) {
                int n = n0 + (tx << 2) + (j & 3) + ((j >> 2) << 6);
                half4 hv;
                hv[0] = (_Float16)(acc[g * 4 + 0][j] * qs);
                hv[1] = (_Float16)(acc[g * 4 + 1][j] * qs);
                hv[2] = (_Float16)(acc[g * 4 + 2][j] * qs);
                hv[3] = (_Float16)(acc[g * 4 + 3][j] * qs);
                *(half4*)(hb + (size_t)n * 64) = hv;
            }
        }
    } else {
#pragma unroll
        for (int i = 0; i < 8; i++) {
            int row = (o0 - 512) + (ty << 2) + (i & 3) + ((i >> 2) << 6);
            _Float16* rb = vF + ((size_t)bz * 256 + row) * Ndim + n0 + (tx << 2);
#pragma unroll
            for (int jg = 0; jg < 2; jg++) {
                half4 hv;
                hv[0] = (_Float16)acc[i][jg * 4 + 0];
                hv[1] = (_Float16)acc[i][jg * 4 + 1];
                hv[2] = (_Float16)acc[i][jg * 4 + 2];
                hv[3] = (_Float16)acc[i][jg * 4 + 3];
                *(half4*)(rb + (jg << 6)) = hv;
            }
        }
    }
}

// ---------------- flash attention, f16 MFMA, LDS-staged K/V ----------------
// 512 linear blocks (XCD-swizzled: one (b,h) per XCD), 256 thr = 4 waves,
// wave w owns q rows [q0+16w, +16). KB=32. Static-max softmax via exp2 with
// the shift folded into the MFMA accumulator init. DPP row-sum (no LDS shfl).
// LDS: K dbuf 2x4KB @0, V dbuf 2x4KB @8192, P 4KB @16384; epilogue aliases @0.
__global__ __launch_bounds__(256) void attn_k(const _Float16* __restrict__ qT,
                                              const _Float16* __restrict__ kT,
                                              const _Float16* __restrict__ vF,
                                              float* __restrict__ outp) {
    __shared__ __align__(16) char smem[20480];
    const int tid = threadIdx.x;
    const int w = tid >> 6, lane = tid & 63;
    const int a = lane >> 4, b_ = lane & 15;
    // XCD swizzle: hardware slot s -> logical block o; XCD (s&7) owns one (b,h)
    const int s = blockIdx.x;
    const int o = ((s & 7) << 6) + (s >> 3);
    const int qt = o & 63;
    const size_t bh = (size_t)(o >> 6);
    const int q0 = qt << 6;
    const _Float16* Qb = qT + bh * (size_t)(Ndim * 64);
    const _Float16* Kb = kT + bh * (size_t)(Ndim * 64);
    const _Float16* Vb = vF + bh * (size_t)(64 * Ndim);

    // Q fragments (scale folded)
    const _Float16* qp = Qb + (size_t)(q0 + w * 16 + b_) * 64 + a * 8;
    half8 qf0 = *(const half8*)(qp);
    half8 qf1 = *(const half8*)(qp + 32);

    // staging geometry: K tile 32x64 f16 (256x16B units), V tile 64x32 f16
    const int ku = (w << 6) + lane;
    const int km = ku >> 3, kj = ku & 7;
    const int kldso = ((km << 3) | (kj ^ (km & 7))) << 4;
    const char* kgp = (const char*)Kb + (size_t)km * 128 + kj * 16;
    const int vu = (w << 6) + lane;
    const int vd = vu >> 2, vj = vu & 3;
    const int vldso = 8192 + (((vd << 2) | (vj ^ ((vd >> 1) & 3))) << 4);
    const char* vgp = (const char*)Vb + (size_t)vd * (Ndim * 2) + vj * 16;

    // fragment read offsets (swizzled to match staging)
    const int swk = b_ & 7;
    const int fv = (b_ >> 1) & 3;
    const int k00o = ((b_ << 3) | (a ^ swk)) << 4;
    const int k01o = ((b_ << 3) | ((a + 4) ^ swk)) << 4;
    const int k10o = (((16 + b_) << 3) | (a ^ swk)) << 4;
    const int k11o = (((16 + b_) << 3) | ((a + 4) ^ swk)) << 4;
    const int v0o = 8192 + (((b_ << 2) | (a ^ fv)) << 4);
    const int prd = (((w * 16 + b_) * 64 + a * 16) ^ ((b_ & 12) << 2));
    char* PsB = smem + 16384;

    f32x4 o0 = {0.f, 0.f, 0.f, 0.f}, o1 = o0, o2 = o0, o3 = o0;
    float lr[4] = {0.f, 0.f, 0.f, 0.f};

    // prologue: stage tile 0 into buffer 0
    {
        f32x4 k0v = *(const f32x4*)kgp;
        f32x4 v0v = *(const f32x4*)vgp;
        kgp += 4096; vgp += 64;
        *(f32x4*)(smem + kldso) = k0v;
        *(f32x4*)(smem + vldso) = v0v;
    }
    __syncthreads();

    for (int it = 0; it < 128; ++it) {
        const int cur = (it & 1) << 12;
        f32x4 kn, vn;
        const bool pf = (it < 127);
        if (pf) {
            kn = *(const f32x4*)kgp; kgp += 4096;
            vn = *(const f32x4*)vgp; vgp += 64;
        }
        const char* Kc = smem + cur;
        half8 k00 = *(const half8*)(Kc + k00o);
        half8 k01 = *(const half8*)(Kc + k01o);
        half8 k10 = *(const half8*)(Kc + k10o);
        half8 k11 = *(const half8*)(Kc + k11o);

        f32x4 s0 = {SINIT, SINIT, SINIT, SINIT}, s1 = s0;
        s0 = __builtin_amdgcn_mfma_f32_16x16x32_f16(qf0, k00, s0, 0, 0, 0);
        s0 = __builtin_amdgcn_mfma_f32_16x16x32_f16(qf1, k01, s0, 0, 0, 0);
        s1 = __builtin_amdgcn_mfma_f32_16x16x32_f16(qf0, k10, s1, 0, 0, 0);
        s1 = __builtin_amdgcn_mfma_f32_16x16x32_f16(qf1, k11, s1, 0, 0, 0);

        // P = 2^s (static-max softmax), row-sum via DPP
        float e0[4], e1[4];
#pragma unroll
        for (int r = 0; r < 4; r++) {
            e0[r] = __builtin_exp2f(s0[r]);
            e1[r] = __builtin_exp2f(s1[r]);
            float rs = e0[r] + e1[r];
            DPP_ADD(rs, 0xB1);   // quad_perm(1,0,3,2)
            DPP_ADD(rs, 0x4E);   // quad_perm(2,3,0,1)
            DPP_ADD(rs, 0x124);  // row_ror:4
            DPP_ADD(rs, 0x128);  // row_ror:8
            lr[r] += rs;
        }
        // P -> LDS f16 (wave-local rows, no barrier)
#pragma unroll
        for (int r = 0; r < 4; r++) {
            int ql = w * 16 + a * 4 + r;
            int base = ql * 64 + b_ * 2;
            int sw = (ql & 12) << 2;
            *(_Float16*)(PsB + (base ^ sw)) = (_Float16)e0[r];
            *(_Float16*)(PsB + ((base + 32) ^ sw)) = (_Float16)e1[r];
        }
        half8 pa = *(half8*)(PsB + prd);
        const char* Vc = smem + cur;
        half8 vv0 = *(const half8*)(Vc + v0o);
        half8 vv1 = *(const half8*)(Vc + v0o + 1024);
        half8 vv2 = *(const half8*)(Vc + v0o + 2048);
        half8 vv3 = *(const half8*)(Vc + v0o + 3072);
        o0 = __builtin_amdgcn_mfma_f32_16x16x32_f16(pa, vv0, o0, 0, 0, 0);
        o1 = __builtin_amdgcn_mfma_f32_16x16x32_f16(pa, vv1, o1, 0, 0, 0);
        o2 = __builtin_amdgcn_mfma_f32_16x16x32_f16(pa, vv2, o2, 0, 0, 0);
        o3 = __builtin_amdgcn_mfma_f32_16x16x32_f16(pa, vv3, o3, 0, 0, 0);

        if (pf) {
            const int nxt = cur ^ 4096;
            *(f32x4*)(smem + nxt + kldso) = kn;
            *(f32x4*)(smem + nxt + vldso) = vn;
        }
        __syncthreads();
    }

    float inv[4];
#pragma unroll
    for (int r = 0; r < 4; r++) inv[r] = 1.0f / lr[r];
    // stage O^T[d][q] f32 in LDS (swizzled), then coalesced store
    char* LoB = smem;
#pragma unroll
    for (int dt = 0; dt < 4; dt++) {
        f32x4 val = (dt == 0) ? o0 : (dt == 1) ? o1 : (dt == 2) ? o2 : o3;
#pragma unroll
        for (int r = 0; r < 4; r++) val[r] *= inv[r];
        int d = 16 * dt + b_;
        int off = (d * 256 + w * 64 + a * 16) ^ ((d & 7) << 4);
        *(f32x4*)(LoB + off) = val;
    }
    __syncthreads();
#pragma unroll
    for (int p = 0; p < 4; p++) {
        int d = p * 16 + (tid >> 4), qc = tid & 15;
        int off = (d * 256 + qc * 16) ^ ((d & 7) << 4);
        f32x4 v = *(f32x4*)(LoB + off);
        *(f32x4*)(outp + (bh * 64 + d) * (size_t)Ndim + q0 + (qc << 2)) = v;
    }
}

// ---------------- proj GEMM (fp32) with bias+residual epilogue ----------------
__global__ __launch_bounds__(256) void gemm_proj_k(const float* __restrict__ WT,
                                                   const float* __restrict__ X,
                                                   float* __restrict__ out,
                                                   const float* __restrict__ bias,
                                                   const float* __restrict__ resid) {
    __shared__ __align__(16) float Ws[32][128];
    __shared__ __align__(16) float Xs[32][128];
    const int tid = threadIdx.x, tx = tid & 15, ty = tid >> 4;
    const int n0 = blockIdx.x << 7, o0 = blockIdx.y << 7;
    const size_t bX = (size_t)blockIdx.z * Cdim * Ndim;
    float acc[8][8] = {};
    for (int k0 = 0; k0 < Cdim; k0 += 32) {
        __syncthreads();
#pragma unroll
        for (int kq = 0; kq < 4; kq++) {
            int f4 = tid + (kq << 8);
            int r = f4 >> 5, cc = (f4 & 31) << 2;
            *(float4*)&Ws[r][cc] = *(const float4*)(WT + (size_t)(k0 + r) * 256 + o0 + cc);
            *(float4*)&Xs[r][cc] = *(const float4*)(X + bX + (size_t)(k0 + r) * Ndim + n0 + cc);
        }
        __syncthreads();
#pragma unroll 4
        for (int kk = 0; kk < 32; kk++) {
            float4 wa = *(const float4*)&Ws[kk][ty << 2];
            float4 wb = *(const float4*)&Ws[kk][(ty << 2) + 64];
            float4 xa = *(const float4*)&Xs[kk][tx << 2];
            float4 xb = *(const float4*)&Xs[kk][(tx << 2) + 64];
            float w[8] = {wa.x, wa.y, wa.z, wa.w, wb.x, wb.y, wb.z, wb.w};
            float xv[8] = {xa.x, xa.y, xa.z, xa.w, xb.x, xb.y, xb.z, xb.w};
#pragma unroll
            for (int i = 0; i < 8; i++)
#pragma unroll
                for (int j = 0; j < 8; j++)
                    acc[i][j] = fmaf(w[i], xv[j], acc[i][j]);
        }
    }
#pragma unroll
    for (int i = 0; i < 8; i++) {
        int o = o0 + (ty << 2) + ((i < 4) ? i : (64 + i - 4));
        size_t rowoff = bX + (size_t)o * Ndim + n0 + (tx << 2);
        float bv = bias[o];
        float4 r0, r1;
        r0.x = acc[i][0] + bv; r0.y = acc[i][1] + bv; r0.z = acc[i][2] + bv; r0.w = acc[i][3] + bv;
        r1.x = acc[i][4] + bv; r1.y = acc[i][5] + bv; r1.z = acc[i][6] + bv; r1.w = acc[i][7] + bv;
        float4 x0 = *(const float4*)(resid + rowoff);
        float4 x1 = *(const float4*)(resid + rowoff + 64);
        r0.x += x0.x; r0.y += x0.y; r0.z += x0.z; r0.w += x0.w;
        r1.x += x1.x; r1.y += x1.y; r1.z += x1.z; r1.w += x1.w;
        *(float4*)(out + rowoff) = r0;
        *(float4*)(out + rowoff + 64) = r1;
    }
}

extern "C" void kernel_launch(void* const* d_in, const int* in_sizes, int n_in,
                              void* d_out, int out_size, void* d_ws, size_t ws_size,
                              hipStream_t stream) {
    (void)in_sizes; (void)n_in; (void)out_size; (void)ws_size;
    const float* x        = (const float*)d_in[0];
    const float* gn_scale = (const float*)d_in[1];
    const float* gn_bias  = (const float*)d_in[2];
    const float* w_qkv    = (const float*)d_in[3];
    const float* w_proj   = (const float*)d_in[4];
    const float* b_proj   = (const float*)d_in[5];
    float* ws    = (float*)d_ws;
    float* stats = ws + WS_STATS;
    float* wtq   = ws + WS_WTQKV;
    float* wtp   = ws + WS_WTPROJ;
    float* hn    = ws + WS_HN;
    _Float16* qT = (_Float16*)(ws + WS_QT);
    _Float16* kT = (_Float16*)(ws + WS_KT);
    _Float16* vF = (_Float16*)(ws + WS_VF);
    float* outp  = (float*)d_out;

    tpose_k<<<dim3(8, 24), dim3(32, 8), 0, stream>>>(w_qkv, wtq, 768, 256);
    tpose_k<<<dim3(8, 8), dim3(32, 8), 0, stream>>>(w_proj, wtp, 256, 256);
    gn_stats_k<<<64, 256, 0, stream>>>(x, stats);
    gn_apply_k<<<2048, 256, 0, stream>>>(x, stats, gn_scale, gn_bias, hn);
    gemm_qkv_k<<<dim3(32, 6, 2), 256, 0, stream>>>(wtq, hn, qT, kT, vF);
    attn_k<<<512, 256, 0, stream>>>(qT, kT, vF, hn);
    gemm_proj_k<<<dim3(32, 2, 2), 256, 0, stream>>>(wtp, hn, outp, b_proj, x);
}

// Round 8
// 214.077 us; speedup vs baseline: 3.6141x; 1.2689x over previous
//
#include <hip/hip_runtime.h>
#include <hip/hip_bf16.h>
#include <math.h>

#define Bdim 2
#define Cdim 256
#define Ndim 4096
#define HEADS 4
#define HDim 64

typedef _Float16 half8 __attribute__((ext_vector_type(8)));
typedef _Float16 half4 __attribute__((ext_vector_type(4)));
typedef float f32x4 __attribute__((ext_vector_type(4)));

// ws layout in floats
static const size_t WS_STATS  = 0;        // 64*2 -> pad 256
static const size_t WS_WTPROJ = 256;      // 256*256 f32 -> ends 65792
static const size_t WS_WHQ    = 65792;    // 768*256 f16 = 98304 fl -> ends 164096
static const size_t WS_HN     = 164096;   // 2*256*4096 f32 (attn out) -> ends 2261248
static const size_t WS_HNT    = 2261248;  // 2*4096*256 f16 -> ends 3309824
static const size_t WS_QT     = 3309824;  // 2*4*4096*64 f16 -> ends 4358400
static const size_t WS_KT     = 4358400;  // -> ends 5406976
static const size_t WS_VF     = 5406976;  // 2*256*4096 f16 -> ends 6455552 (~25.8 MB)

// q scale: 1/sqrt(64) * log2(e); MFMA acc init -8.65617 gives P = e^(S_true-6),
// the e^-6 cancels in the normalize.
#define QSCALE 0.18033688f
#define SINIT  -8.65617025f

// ---------------- group-norm stats ----------------
__global__ __launch_bounds__(256) void gn_stats_k(const float* __restrict__ x,
                                                  float* __restrict__ stats) {
    int g = blockIdx.x;
    const float4* p4 = (const float4*)(x + (size_t)g * 32768);
    int tid = threadIdx.x;
    float s = 0.f, ss = 0.f;
#pragma unroll 8
    for (int w = 0; w < 32; w++) {
        float4 v = p4[tid + w * 256];
        s += v.x + v.y + v.z + v.w;
        ss += v.x * v.x + v.y * v.y + v.z * v.z + v.w * v.w;
    }
#pragma unroll
    for (int m = 1; m < 64; m <<= 1) {
        s += __shfl_xor(s, m);
        ss += __shfl_xor(ss, m);
    }
    __shared__ float ws_s[4], ws_ss[4];
    int wid = tid >> 6, lane = tid & 63;
    if (lane == 0) { ws_s[wid] = s; ws_ss[wid] = ss; }
    __syncthreads();
    if (tid == 0) {
        float ts = ws_s[0] + ws_s[1] + ws_s[2] + ws_s[3];
        float tss = ws_ss[0] + ws_ss[1] + ws_ss[2] + ws_ss[3];
        float mean = ts * (1.0f / 32768.0f);
        float var = tss * (1.0f / 32768.0f) - mean * mean;
        stats[2 * g] = mean;
        stats[2 * g + 1] = rsqrtf(var + 1e-5f);
    }
}

// ---------------- GN apply + transpose -> hnT[b][n][c] f16 ----------------
// tile 64c x 64n, grid (64 ntiles, 4 ctiles, 2 b)
__global__ __launch_bounds__(256) void gnT_k(const float* __restrict__ x,
                                             const float* __restrict__ stats,
                                             const float* __restrict__ scale,
                                             const float* __restrict__ bias,
                                             _Float16* __restrict__ hnT) {
    __shared__ float t[64][68];
    const int tid = threadIdx.x;
    const int n0 = blockIdx.x << 6, c0 = blockIdx.y << 6, bz = blockIdx.z;
    const int cr = tid >> 2, q4 = tid & 3;
    const int c = c0 + cr;
    const int g = bz * 32 + (c >> 3);
    const float sc = stats[2 * g + 1] * scale[c];
    const float bi = bias[c] - stats[2 * g] * sc;
    const float* base = x + ((size_t)(bz * 256 + c)) * Ndim + n0;
#pragma unroll
    for (int k = 0; k < 4; k++) {
        int j = k * 4 + q4;
        float4 v = *(const float4*)(base + j * 4);
        v.x = v.x * sc + bi; v.y = v.y * sc + bi; v.z = v.z * sc + bi; v.w = v.w * sc + bi;
        *(float4*)&t[cr][j * 4] = v;
    }
    __syncthreads();
    const int nr = tid >> 2, ch = tid & 3;
    half8 o0, o1;
#pragma unroll
    for (int j = 0; j < 8; j++) o0[j] = (_Float16)t[ch * 16 + j][nr];
#pragma unroll
    for (int j = 0; j < 8; j++) o1[j] = (_Float16)t[ch * 16 + 8 + j][nr];
    _Float16* dst = hnT + ((size_t)bz * Ndim + n0 + nr) * 256 + c0 + ch * 16;
    *(half8*)(dst) = o0;
    *(half8*)(dst + 8) = o1;
}

// ---------------- w_qkv f32 -> f16 (QSCALE folded for q rows) ----------------
__global__ __launch_bounds__(256) void wcvt_k(const float* __restrict__ w,
                                              _Float16* __restrict__ wh) {
    int i = blockIdx.x * 256 + threadIdx.x;
    float v = w[i];
    if ((i >> 8) < 256) v *= QSCALE;
    wh[i] = (_Float16)v;
}

// ---------------- weight transpose (w_proj only): W[O][C] -> WT[C][O] --------
__global__ __launch_bounds__(256) void tpose_k(const float* __restrict__ W,
                                               float* __restrict__ WT,
                                               int O, int Cc) {
    __shared__ float t[32][33];
    int c0 = blockIdx.x * 32, o0 = blockIdx.y * 32;
    int tx = threadIdx.x, ty = threadIdx.y;
#pragma unroll
    for (int k = 0; k < 4; k++) {
        int o = o0 + ty + k * 8;
        t[ty + k * 8][tx] = W[(size_t)o * Cc + c0 + tx];
    }
    __syncthreads();
#pragma unroll
    for (int k = 0; k < 4; k++) {
        int c = c0 + ty + k * 8;
        WT[(size_t)c * O + o0 + tx] = t[tx][ty + k * 8];
    }
}

// ---------------- QKV GEMM, f16 MFMA ----------------
// out[o][n] = sum_c wh[o][c] * hnT[n][c]; grid (32 n-tiles, 6 o-tiles, 2 b),
// 256 thr = 4 waves (2x2), tile 128x128, BK=32, dbuf LDS.
__global__ __launch_bounds__(256) void gemm_qkv16_k(const _Float16* __restrict__ wh,
                                                    const _Float16* __restrict__ hnT,
                                                    _Float16* __restrict__ qT,
                                                    _Float16* __restrict__ kT,
                                                    _Float16* __restrict__ vF) {
    __shared__ __align__(16) char smem[32768];  // W dbuf 2x8K @0, X dbuf 2x8K @16384
    const int tid = threadIdx.x, w = tid >> 6, lane = tid & 63;
    const int a = lane >> 4, b_ = lane & 15;
    const int wo = w >> 1, wn = w & 1;
    const int n0 = blockIdx.x << 7, o0 = blockIdx.y << 7, bz = blockIdx.z;

    const int srow = tid >> 1, su = (tid & 1) << 1;
    const _Float16* wg = wh + (size_t)(o0 + srow) * 256 + (su << 3);
    const _Float16* xg = hnT + ((size_t)(bz * Ndim + n0 + srow)) * 256 + (su << 3);
    const int wd0 = srow * 64 + ((su ^ (srow & 3)) << 4);
    const int wd1 = srow * 64 + (((su + 1) ^ (srow & 3)) << 4);

    {
        half8 a0 = *(const half8*)(wg), a1 = *(const half8*)(wg + 8);
        half8 b0 = *(const half8*)(xg), b1 = *(const half8*)(xg + 8);
        *(half8*)(smem + wd0) = a0; *(half8*)(smem + wd1) = a1;
        *(half8*)(smem + 16384 + wd0) = b0; *(half8*)(smem + 16384 + wd1) = b1;
    }
    __syncthreads();

    f32x4 acc[4][4] = {};
    const int fa = (a ^ (b_ & 3)) << 4;
    int arow[4], brow[4];
#pragma unroll
    for (int t = 0; t < 4; t++) {
        arow[t] = (wo * 64 + t * 16 + b_) * 64 + fa;
        brow[t] = 16384 + (wn * 64 + t * 16 + b_) * 64 + fa;
    }

    for (int kk = 0; kk < 8; kk++) {
        const int cur = (kk & 1) * 8192;
        half8 nw0, nw1, nx0, nx1;
        const bool pf = (kk < 7);
        if (pf) {
            const _Float16* wp = wg + (kk + 1) * 32;
            const _Float16* xp = xg + (kk + 1) * 32;
            nw0 = *(const half8*)(wp); nw1 = *(const half8*)(wp + 8);
            nx0 = *(const half8*)(xp); nx1 = *(const half8*)(xp + 8);
        }
        half8 af[4], bf[4];
#pragma unroll
        for (int t = 0; t < 4; t++) {
            af[t] = *(const half8*)(smem + cur + arow[t]);
            bf[t] = *(const half8*)(smem + cur + brow[t]);
        }
#pragma unroll
        for (int i = 0; i < 4; i++)
#pragma unroll
            for (int j = 0; j < 4; j++)
                acc[i][j] = __builtin_amdgcn_mfma_f32_16x16x32_f16(af[i], bf[j], acc[i][j], 0, 0, 0);
        if (pf) {
            const int nxt = cur ^ 8192;
            *(half8*)(smem + nxt + wd0) = nw0; *(half8*)(smem + nxt + wd1) = nw1;
            *(half8*)(smem + 16384 + nxt + wd0) = nx0; *(half8*)(smem + 16384 + nxt + wd1) = nx1;
        }
        __syncthreads();
    }

    if (o0 < 512) {
        // q/k: LDS-bounce to [n][o] f16 (8B-unit XOR swizzle), then coalesced rows
#pragma unroll
        for (int ot = 0; ot < 4; ot++) {
#pragma unroll
            for (int nt = 0; nt < 4; nt++) {
                int n = wn * 64 + nt * 16 + b_;
                int u = wo * 16 + ot * 4 + a;  // 8B unit along o (o = u*4 + r)
                half4 hv;
                hv[0] = (_Float16)acc[ot][nt][0]; hv[1] = (_Float16)acc[ot][nt][1];
                hv[2] = (_Float16)acc[ot][nt][2]; hv[3] = (_Float16)acc[ot][nt][3];
                *(half4*)(smem + n * 256 + ((u ^ (n & 31)) << 3)) = hv;
            }
        }
        __syncthreads();
        _Float16* dst = (o0 >= 256) ? kT : qT;
        const int headbase = (o0 >> 6) & 3;
#pragma unroll
        for (int hsel = 0; hsel < 2; hsel++) {
            _Float16* hb = dst + ((size_t)(bz * 4 + headbase + hsel)) * (Ndim * 64);
#pragma unroll
            for (int p = 0; p < 4; p++) {
                int n = p * 32 + (tid >> 3), j = tid & 7;
                int u0 = hsel * 16 + j * 2;
                half4 lo = *(const half4*)(smem + n * 256 + ((u0 ^ (n & 31)) << 3));
                half4 hi = *(const half4*)(smem + n * 256 + (((u0 + 1) ^ (n & 31)) << 3));
                half8 o8;
                o8[0] = lo[0]; o8[1] = lo[1]; o8[2] = lo[2]; o8[3] = lo[3];
                o8[4] = hi[0]; o8[5] = hi[1]; o8[6] = hi[2]; o8[7] = hi[3];
                *(half8*)(hb + (size_t)(n0 + n) * 64 + j * 8) = o8;
            }
        }
    } else {
        // v: direct b16 stores (16-lane 32B segments)
        _Float16* vb = vF + ((size_t)bz * 256 + (o0 - 512)) * Ndim;
#pragma unroll
        for (int ot = 0; ot < 4; ot++)
#pragma unroll
            for (int nt = 0; nt < 4; nt++)
#pragma unroll
                for (int r = 0; r < 4; r++)
                    vb[(size_t)(wo * 64 + ot * 16 + a * 4 + r) * Ndim +
                       n0 + wn * 64 + nt * 16 + b_] = (_Float16)acc[ot][nt][r];
    }
}

// ---------------- flash attention: swapped QK^T, in-register P ----------------
// 512 blocks (XCD-swizzled), 4 waves, wave w owns q rows [q0+16w,+16), KB=32.
// S^T = mfma32(K,Q) puts q=lane&15; P stays in registers and feeds two
// mfma_16x16x16 PV ops (A-frag k=4a+i == S^T row m=4a+r). Row-sum is a per-lane
// scalar reduced once at the end. LDS: K dbuf 2x4KB @0, V dbuf 2x4KB @8192.
__global__ __launch_bounds__(256) void attn_k(const _Float16* __restrict__ qT,
                                              const _Float16* __restrict__ kT,
                                              const _Float16* __restrict__ vF,
                                              float* __restrict__ outp) {
    __shared__ __align__(16) char smem[16384];
    const int tid = threadIdx.x;
    const int w = tid >> 6, lane = tid & 63;
    const int a = lane >> 4, b_ = lane & 15;
    const int s = blockIdx.x;
    const int o = ((s & 7) << 6) + (s >> 3);
    const int qt = o & 63;
    const size_t bh = (size_t)(o >> 6);
    const int q0 = qt << 6;
    const _Float16* Qb = qT + bh * (size_t)(Ndim * 64);
    const _Float16* Kb = kT + bh * (size_t)(Ndim * 64);
    const _Float16* Vb = vF + bh * (size_t)(64 * Ndim);

    const _Float16* qp = Qb + (size_t)(q0 + w * 16 + b_) * 64 + a * 8;
    half8 qf0 = *(const half8*)(qp);
    half8 qf1 = *(const half8*)(qp + 32);

    // staging: K tile 32x64, V tile 64x32 (both f16, swizzled)
    const int km = tid >> 3, kj = tid & 7;
    const int kldso = ((km << 3) | (kj ^ (km & 7))) << 4;
    const char* kgp = (const char*)Kb + (size_t)km * 128 + kj * 16;
    const int vd = tid >> 2, vj = tid & 3;
    const int vldso = 8192 + (((vd << 2) | (vj ^ ((vd >> 1) & 3))) << 4);
    const char* vgp = (const char*)Vb + (size_t)vd * (Ndim * 2) + vj * 16;

    // K b128 fragment offsets
    const int swk = b_ & 7;
    const int k00o = ((b_ << 3) | (a ^ swk)) << 4;
    const int k01o = ((b_ << 3) | ((a + 4) ^ swk)) << 4;
    const int k10o = (((16 + b_) << 3) | (a ^ swk)) << 4;
    const int k11o = (((16 + b_) << 3) | ((a + 4) ^ swk)) << 4;
    // V b64 fragment offsets: row d=16dt+b_, lo m=4a..4a+3, hi m=16+4a..
    const int xsw = (b_ >> 1) & 3;
    int vlo[4], vhi[4];
#pragma unroll
    for (int dt = 0; dt < 4; dt++) {
        int d = 16 * dt + b_;
        vlo[dt] = 8192 + d * 64 + ((((a >> 1)) ^ xsw) << 4) + ((a & 1) << 3);
        vhi[dt] = 8192 + d * 64 + (((2 + (a >> 1)) ^ xsw) << 4) + ((a & 1) << 3);
    }

    f32x4 oa[4] = {};
    float lr = 0.f;

    {
        f32x4 k0v = *(const f32x4*)kgp;
        f32x4 v0v = *(const f32x4*)vgp;
        kgp += 4096; vgp += 64;
        *(f32x4*)(smem + kldso) = k0v;
        *(f32x4*)(smem + vldso) = v0v;
    }
    __syncthreads();

    for (int it = 0; it < 128; ++it) {
        const int cur = (it & 1) << 12;
        f32x4 kn, vn;
        const bool pf = (it < 127);
        if (pf) {
            kn = *(const f32x4*)kgp; kgp += 4096;
            vn = *(const f32x4*)vgp; vgp += 64;
        }
        const char* Kc = smem + cur;
        half8 k00 = *(const half8*)(Kc + k00o);
        half8 k01 = *(const half8*)(Kc + k01o);
        half8 k10 = *(const half8*)(Kc + k10o);
        half8 k11 = *(const half8*)(Kc + k11o);

        // swapped: S^T[m][q], lane holds q=b_, m=a*4+r (+16 for s1)
        f32x4 s0 = {SINIT, SINIT, SINIT, SINIT}, s1 = s0;
        s0 = __builtin_amdgcn_mfma_f32_16x16x32_f16(k00, qf0, s0, 0, 0, 0);
        s0 = __builtin_amdgcn_mfma_f32_16x16x32_f16(k01, qf1, s0, 0, 0, 0);
        s1 = __builtin_amdgcn_mfma_f32_16x16x32_f16(k10, qf0, s1, 0, 0, 0);
        s1 = __builtin_amdgcn_mfma_f32_16x16x32_f16(k11, qf1, s1, 0, 0, 0);

        float e0[4], e1[4];
#pragma unroll
        for (int r = 0; r < 4; r++) {
            e0[r] = __builtin_exp2f(s0[r]);
            e1[r] = __builtin_exp2f(s1[r]);
        }
        lr += ((e0[0] + e0[1]) + (e0[2] + e0[3])) + ((e1[0] + e1[1]) + (e1[2] + e1[3]));

        half4 alo, ahi;
#pragma unroll
        for (int r = 0; r < 4; r++) { alo[r] = (_Float16)e0[r]; ahi[r] = (_Float16)e1[r]; }

        const char* Vc = smem + cur;
#pragma unroll
        for (int dt = 0; dt < 4; dt++) {
            half4 bl = *(const half4*)(Vc + vlo[dt]);
            half4 bh2 = *(const half4*)(Vc + vhi[dt]);
            oa[dt] = __builtin_amdgcn_mfma_f32_16x16x16f16(alo, bl, oa[dt], 0, 0, 0);
            oa[dt] = __builtin_amdgcn_mfma_f32_16x16x16f16(ahi, bh2, oa[dt], 0, 0, 0);
        }

        if (pf) {
            const int nxt = cur ^ 4096;
            *(f32x4*)(smem + nxt + kldso) = kn;
            *(f32x4*)(smem + nxt + vldso) = vn;
        }
        __syncthreads();
    }

    // one-time row-sum reduce: lane's partial covers its m-subsets for q=b_
    float lrt = lr;
    lrt += __shfl_xor(lrt, 16);
    lrt += __shfl_xor(lrt, 32);
    float inv[4];
#pragma unroll
    for (int r = 0; r < 4; r++) inv[r] = 1.0f / __shfl(lrt, a * 4 + r);

    // epilogue: stage O^T[d][q] f32 (swizzled), coalesced store
    char* LoB = smem;
#pragma unroll
    for (int dt = 0; dt < 4; dt++) {
        f32x4 val = oa[dt];
#pragma unroll
        for (int r = 0; r < 4; r++) val[r] *= inv[r];
        int d = 16 * dt + b_;
        int off = (d * 256 + w * 64 + a * 16) ^ ((d & 7) << 4);
        *(f32x4*)(LoB + off) = val;
    }
    __syncthreads();
#pragma unroll
    for (int p = 0; p < 4; p++) {
        int d = p * 16 + (tid >> 4), qc = tid & 15;
        int off = (d * 256 + qc * 16) ^ ((d & 7) << 4);
        f32x4 v = *(const f32x4*)(LoB + off);
        *(f32x4*)(outp + (bh * 64 + d) * (size_t)Ndim + q0 + (qc << 2)) = v;
    }
}

// ---------------- proj GEMM (fp32) with bias+residual epilogue ----------------
__global__ __launch_bounds__(256) void gemm_proj_k(const float* __restrict__ WT,
                                                   const float* __restrict__ X,
                                                   float* __restrict__ out,
                                                   const float* __restrict__ bias,
                                                   const float* __restrict__ resid) {
    __shared__ __align__(16) float Ws[32][128];
    __shared__ __align__(16) float Xs[32][128];
    const int tid = threadIdx.x, tx = tid & 15, ty = tid >> 4;
    const int n0 = blockIdx.x << 7, o0 = blockIdx.y << 7;
    const size_t bX = (size_t)blockIdx.z * Cdim * Ndim;
    float acc[8][8] = {};
    for (int k0 = 0; k0 < Cdim; k0 += 32) {
        __syncthreads();
#pragma unroll
        for (int kq = 0; kq < 4; kq++) {
            int f4 = tid + (kq << 8);
            int r = f4 >> 5, cc = (f4 & 31) << 2;
            *(float4*)&Ws[r][cc] = *(const float4*)(WT + (size_t)(k0 + r) * 256 + o0 + cc);
            *(float4*)&Xs[r][cc] = *(const float4*)(X + bX + (size_t)(k0 + r) * Ndim + n0 + cc);
        }
        __syncthreads();
#pragma unroll 4
        for (int kk = 0; kk < 32; kk++) {
            float4 wa = *(const float4*)&Ws[kk][ty << 2];
            float4 wb = *(const float4*)&Ws[kk][(ty << 2) + 64];
            float4 xa = *(const float4*)&Xs[kk][tx << 2];
            float4 xb = *(const float4*)&Xs[kk][(tx << 2) + 64];
            float wv[8] = {wa.x, wa.y, wa.z, wa.w, wb.x, wb.y, wb.z, wb.w};
            float xv[8] = {xa.x, xa.y, xa.z, xa.w, xb.x, xb.y, xb.z, xb.w};
#pragma unroll
            for (int i = 0; i < 8; i++)
#pragma unroll
                for (int j = 0; j < 8; j++)
                    acc[i][j] = fmaf(wv[i], xv[j], acc[i][j]);
        }
    }
#pragma unroll
    for (int i = 0; i < 8; i++) {
        int o = o0 + (ty << 2) + ((i < 4) ? i : (64 + i - 4));
        size_t rowoff = bX + (size_t)o * Ndim + n0 + (tx << 2);
        float bv = bias[o];
        float4 r0, r1;
        r0.x = acc[i][0] + bv; r0.y = acc[i][1] + bv; r0.z = acc[i][2] + bv; r0.w = acc[i][3] + bv;
        r1.x = acc[i][4] + bv; r1.y = acc[i][5] + bv; r1.z = acc[i][6] + bv; r1.w = acc[i][7] + bv;
        float4 x0 = *(const float4*)(resid + rowoff);
        float4 x1 = *(const float4*)(resid + rowoff + 64);
        r0.x += x0.x; r0.y += x0.y; r0.z += x0.z; r0.w += x0.w;
        r1.x += x1.x; r1.y += x1.y; r1.z += x1.z; r1.w += x1.w;
        *(float4*)(out + rowoff) = r0;
        *(float4*)(out + rowoff + 64) = r1;
    }
}

extern "C" void kernel_launch(void* const* d_in, const int* in_sizes, int n_in,
                              void* d_out, int out_size, void* d_ws, size_t ws_size,
                              hipStream_t stream) {
    (void)in_sizes; (void)n_in; (void)out_size; (void)ws_size;
    const float* x        = (const float*)d_in[0];
    const float* gn_scale = (const float*)d_in[1];
    const float* gn_bias  = (const float*)d_in[2];
    const float* w_qkv    = (const float*)d_in[3];
    const float* w_proj   = (const float*)d_in[4];
    const float* b_proj   = (const float*)d_in[5];
    float* ws    = (float*)d_ws;
    float* stats = ws + WS_STATS;
    float* wtp   = ws + WS_WTPROJ;
    _Float16* whq = (_Float16*)(ws + WS_WHQ);
    float* hn    = ws + WS_HN;
    _Float16* hnT = (_Float16*)(ws + WS_HNT);
    _Float16* qT = (_Float16*)(ws + WS_QT);
    _Float16* kT = (_Float16*)(ws + WS_KT);
    _Float16* vF = (_Float16*)(ws + WS_VF);
    float* outp  = (float*)d_out;

    gn_stats_k<<<64, 256, 0, stream>>>(x, stats);
    gnT_k<<<dim3(64, 4, 2), 256, 0, stream>>>(x, stats, gn_scale, gn_bias, hnT);
    wcvt_k<<<768, 256, 0, stream>>>(w_qkv, whq);
    tpose_k<<<dim3(8, 8), dim3(32, 8), 0, stream>>>(w_proj, wtp, 256, 256);
    gemm_qkv16_k<<<dim3(32, 6, 2), 256, 0, stream>>>(whq, hnT, qT, kT, vF);
    attn_k<<<512, 256, 0, stream>>>(qT, kT, vF, hn);
    gemm_proj_k<<<dim3(32, 2, 2), 256, 0, stream>>>(wtp, hn, outp, b_proj, x);
}